// Round 1
// baseline (653.187 us; speedup 1.0000x reference)
//
#include <hip/hip_runtime.h>
#include <math.h>

#define EPS 1e-15f
#define D 128
#define NTYPES 4
#define WPB 4            // waves per 256-thread block
#define NBLOCKS 2048     // 8192 waves total -> 16 rows/wave at B=131072

// Latency-hiding rewrite: grid-stride waves with a 4-deep rolling pipeline.
//   X(n+3): issue start_node + sample-index loads        (independent loads)
//   Y(n+2): issue node_types[snode] (dependent hop #2, 1 iter of slack)
//   Z(n+1): issue the 8 end-row gathers + start row      (t ready, 1 iter slack)
//   C(n)  : wait gathers (issued a full iteration ago), compute, store
// Gather fragments double-buffered in registers (eA/eB), statically indexed.
__global__ __launch_bounds__(256) void mp2v_kernel(
    const float* __restrict__ start_embeds,
    const float* __restrict__ end_embeds,
    const int* __restrict__ start_node,
    const int* __restrict__ pos_samples,
    const int* __restrict__ neg_samples,
    const int* __restrict__ node_types,
    float* __restrict__ out,
    int nrows)
{
    const int lane = threadIdx.x & 63;
    const int half = lane >> 5;            // 0 or 1
    const int m    = lane & 31;            // lane within half-wave
    const int wid  = blockIdx.x * WPB + (threadIdx.x >> 6);
    const int nw   = gridDim.x * WPB;

    if (wid >= nrows) return;
    const int iters = (nrows - 1 - wid) / nw + 1;

#define ROWN(n) (wid + (n) * nw)

    // X: independent index loads (clamped so tail prefetches stay in-bounds)
#define STAGE_X(n, sn, mi)                                          \
    {   int r_ = ROWN(n); if (r_ >= nrows) r_ = nrows - 1;          \
        sn = start_node[r_];                                        \
        mi = 0;                                                     \
        if (lane < 5)       mi = pos_samples[r_ * 5 + lane];        \
        else if (lane < 15) mi = neg_samples[r_ * 10 + (lane - 5)]; }

    // Z: issue all 9 gather instructions (8 KB end rows + 0.5 KB start row)
#define STAGE_Z(sn, mi, tt, e4, s4)                                 \
    {   s4 = ((const float4*)(start_embeds + (size_t)(sn) * D))[m]; \
        _Pragma("unroll")                                           \
        for (int i_ = 0; i_ < 8; ++i_) {                            \
            int src_ = 2 * i_ + half; if (src_ > 14) src_ = 14;     \
            const int idx_ = __shfl((mi), src_);                    \
            e4[i_] = ((const float4*)(end_embeds +                  \
                     ((size_t)idx_ * NTYPES + (tt)) * D))[m];       \
        }                                                           }

    // C: identical math to the verified kernel (absmax-preserving)
#define STAGE_C(n, e4, s4)                                          \
    {   float posAcc = 0.0f, negAcc = 0.0f;                         \
        _Pragma("unroll")                                           \
        for (int i_ = 0; i_ < 8; ++i_) {                            \
            const float p0 = __fmul_rn(e4[i_].x, s4.x);             \
            const float p1 = __fmul_rn(e4[i_].y, s4.y);             \
            const float p2 = __fmul_rn(e4[i_].z, s4.z);             \
            const float p3 = __fmul_rn(e4[i_].w, s4.w);             \
            float p = __fadd_rn(__fadd_rn(p0, p1), __fadd_rn(p2, p3)); \
            p = __fadd_rn(p, __shfl_xor(p, 1));                     \
            p = __fadd_rn(p, __shfl_xor(p, 2));                     \
            p = __fadd_rn(p, __shfl_xor(p, 4));                     \
            p = __fadd_rn(p, __shfl_xor(p, 8));                     \
            p = __fadd_rn(p, __shfl_xor(p, 16));                    \
            const float pr = 1.0f / (1.0f + expf(-p));              \
            const int  s_    = 2 * i_ + half;                       \
            const bool isPos = (s_ < 5);                            \
            const bool valid = (s_ < 15);                           \
            const float arg = isPos ? pr : (1.0f - pr);             \
            const float lg  = logf(arg + EPS);                      \
            posAcc += (isPos && valid) ? lg : 0.0f;                 \
            negAcc += (!isPos && valid) ? lg : 0.0f;                \
        }                                                           \
        posAcc += __shfl_xor(posAcc, 32);                           \
        negAcc += __shfl_xor(negAcc, 32);                           \
        if (lane == 0)                                              \
            out[ROWN(n)] = -(posAcc / 5.0f) - (negAcc / 10.0f);     }

    // ---- pipeline state ----
    int sn0, mi0, t0;
    int sn1, mi1, t1;
    int sn2, mi2, t2;
    int sn3, mi3;
    float4 eA[8], eB[8];
    float4 sA, sB;

    // prologue: X(0..2), Y(0..1), Z(0)
    STAGE_X(0, sn0, mi0);
    STAGE_X(1, sn1, mi1);
    STAGE_X(2, sn2, mi2);
    t0 = node_types[sn0];          // only exposed dependent wait, once per wave
    t1 = node_types[sn1];
    STAGE_Z(sn0, mi0, t0, eA, sA); // row-0 gathers in flight

    int n = 0;
    for (; n + 1 < iters; n += 2) {
        // even: compute A(n), fill B(n+1)
        STAGE_X(n + 3, sn3, mi3);
        t2 = node_types[sn2];
        STAGE_Z(sn1, mi1, t1, eB, sB);
        STAGE_C(n, eA, sA);
        sn1 = sn2; mi1 = mi2; t1 = t2;
        sn2 = sn3; mi2 = mi3;

        // odd: compute B(n+1), fill A(n+2)
        STAGE_X(n + 4, sn3, mi3);
        t2 = node_types[sn2];
        if (n + 2 < iters) STAGE_Z(sn1, mi1, t1, eA, sA);
        STAGE_C(n + 1, eB, sB);
        sn1 = sn2; mi1 = mi2; t1 = t2;
        sn2 = sn3; mi2 = mi3;
    }
    if (n < iters) {               // odd-iters tail: A buffer is already filled
        STAGE_C(n, eA, sA);
    }

#undef STAGE_C
#undef STAGE_Z
#undef STAGE_X
#undef ROWN
}

extern "C" void kernel_launch(void* const* d_in, const int* in_sizes, int n_in,
                              void* d_out, int out_size, void* d_ws, size_t ws_size,
                              hipStream_t stream) {
    const float* start_embeds = (const float*)d_in[0];
    const float* end_embeds   = (const float*)d_in[1];
    const int*   start_node   = (const int*)d_in[2];
    const int*   pos_samples  = (const int*)d_in[3];
    const int*   neg_samples  = (const int*)d_in[4];
    const int*   node_types   = (const int*)d_in[5];
    float* out = (float*)d_out;

    const int nrows = out_size;              // B = 131072 (loss is [B])
    int blocks = (nrows + WPB - 1) / WPB;
    if (blocks > NBLOCKS) blocks = NBLOCKS;
    mp2v_kernel<<<blocks, 256, 0, stream>>>(start_embeds, end_embeds, start_node,
                                            pos_samples, neg_samples, node_types,
                                            out, nrows);
}